// Round 1
// baseline (1410.891 us; speedup 1.0000x reference)
//
#include <hip/hip_runtime.h>

// Problem constants
#define D_MODEL 1024
#define SEQ     2048
#define BATCH   2
#define NH      8
#define HD      128   // D_MODEL / NH
#define MTOT    4096  // BATCH * SEQ

// Workspace layout (float offsets)
#define WS_Q 0
#define WS_K 4194304    // B*H*L*HD = 2*8*2048*128
#define WS_V 8388608
#define WS_A 12582912   // attention output, [b][l][h*128+c]
#define WS_R 16777216   // pre-LN result

__device__ __forceinline__ float4 ldg4(const float* p) {
  return *reinterpret_cast<const float4*>(p);
}

__device__ __forceinline__ float getc(const float4& v, int i) {
  switch (i) { case 0: return v.x; case 1: return v.y; case 2: return v.z; default: return v.w; }
}

// ---------------------------------------------------------------------------
// GEMM core: C[128x128] tile = X[128xK] * W[Kx128], K=1024, BK=16, 256 thr.
// Double-buffered LDS, 8x8 per-thread micro-tile split 2x2 of 4x4 (bank-friendly).
// ---------------------------------------------------------------------------
__device__ __forceinline__ void gemm_core_1024(const float* __restrict__ X,
                                               const float* __restrict__ W,
                                               int m0, int n0,
                                               float acc[2][2][4][4]) {
  __shared__ float As[2][16][132];  // [buf][k][m], pad 4
  __shared__ float Bs[2][16][132];  // [buf][k][n]
  const int t  = threadIdx.x;
  const int tx = t & 15, ty = t >> 4;
  const int ar = t >> 1, ac = (t & 1) * 8;   // A loader: row 0..127, col 0/8
  const int br = t >> 4, bc = (t & 15) * 8;  // B loader: row 0..15, col step 8

#pragma unroll
  for (int a = 0; a < 2; ++a)
#pragma unroll
    for (int b = 0; b < 2; ++b)
#pragma unroll
      for (int i = 0; i < 4; ++i)
#pragma unroll
        for (int j = 0; j < 4; ++j) acc[a][b][i][j] = 0.f;

  const float* Ap = X + (m0 + ar) * D_MODEL + ac;
  const float* Bp = W + br * D_MODEL + n0 + bc;

  float4 a0 = ldg4(Ap), a1 = ldg4(Ap + 4);
  float4 b0 = ldg4(Bp), b1 = ldg4(Bp + 4);
  {
    float av[8] = {a0.x, a0.y, a0.z, a0.w, a1.x, a1.y, a1.z, a1.w};
#pragma unroll
    for (int i = 0; i < 8; ++i) As[0][ac + i][ar] = av[i];  // transpose to [k][m]
    *reinterpret_cast<float4*>(&Bs[0][br][bc])     = b0;
    *reinterpret_cast<float4*>(&Bs[0][br][bc + 4]) = b1;
  }

  const int NSTEP = D_MODEL / 16;
  for (int ks = 0; ks < NSTEP; ++ks) {
    __syncthreads();
    const int cb = ks & 1;
    if (ks + 1 < NSTEP) {  // prefetch next tile into registers
      a0 = ldg4(Ap + (ks + 1) * 16);
      a1 = ldg4(Ap + (ks + 1) * 16 + 4);
      b0 = ldg4(Bp + (ks + 1) * 16 * D_MODEL);
      b1 = ldg4(Bp + (ks + 1) * 16 * D_MODEL + 4);
    }
#pragma unroll
    for (int k = 0; k < 16; ++k) {
      float4 xa0 = *reinterpret_cast<const float4*>(&As[cb][k][ty * 4]);
      float4 xa1 = *reinterpret_cast<const float4*>(&As[cb][k][64 + ty * 4]);
      float4 xb0 = *reinterpret_cast<const float4*>(&Bs[cb][k][tx * 4]);
      float4 xb1 = *reinterpret_cast<const float4*>(&Bs[cb][k][64 + tx * 4]);
      float aa[2][4] = {{xa0.x, xa0.y, xa0.z, xa0.w}, {xa1.x, xa1.y, xa1.z, xa1.w}};
      float bb[2][4] = {{xb0.x, xb0.y, xb0.z, xb0.w}, {xb1.x, xb1.y, xb1.z, xb1.w}};
#pragma unroll
      for (int ri = 0; ri < 2; ++ri)
#pragma unroll
        for (int i = 0; i < 4; ++i)
#pragma unroll
          for (int ci = 0; ci < 2; ++ci)
#pragma unroll
            for (int j = 0; j < 4; ++j)
              acc[ri][ci][i][j] = fmaf(aa[ri][i], bb[ci][j], acc[ri][ci][i][j]);
    }
    if (ks + 1 < NSTEP) {
      const int nb = cb ^ 1;
      float av[8] = {a0.x, a0.y, a0.z, a0.w, a1.x, a1.y, a1.z, a1.w};
#pragma unroll
      for (int i = 0; i < 8; ++i) As[nb][ac + i][ar] = av[i];
      *reinterpret_cast<float4*>(&Bs[nb][br][bc])     = b0;
      *reinterpret_cast<float4*>(&Bs[nb][br][bc + 4]) = b1;
    }
  }
}

// ---------------------------------------------------------------------------
// QKV projection: z=0: Q=de@Wq+bq, z=1: K=en@Wk+bk, z=2: V=en@Wv+bv.
// Epilogue de-interleaves the faithful head split (head = channel % 8):
//   dst[((b*8 + n%8)*2048 + l)*128 + n/8]
// ---------------------------------------------------------------------------
__global__ __launch_bounds__(256) void qkv_kernel(const float* __restrict__ de,
                                                  const float* __restrict__ en,
                                                  const float* __restrict__ Wq, const float* __restrict__ bq,
                                                  const float* __restrict__ Wk, const float* __restrict__ bk,
                                                  const float* __restrict__ Wv, const float* __restrict__ bv,
                                                  float* __restrict__ ws) {
  const int z = blockIdx.z;
  const float* X    = (z == 0) ? de : en;
  const float* W    = (z == 0) ? Wq : (z == 1) ? Wk : Wv;
  const float* bias = (z == 0) ? bq : (z == 1) ? bk : bv;
  float* dst = ws + z * 4194304;
  const int m0 = blockIdx.y * 128, n0 = blockIdx.x * 128;
  float acc[2][2][4][4];
  gemm_core_1024(X, W, m0, n0, acc);
  const int t = threadIdx.x, tx = t & 15, ty = t >> 4;
#pragma unroll
  for (int ri = 0; ri < 2; ++ri)
#pragma unroll
    for (int i = 0; i < 4; ++i) {
      const int m = m0 + ri * 64 + ty * 4 + i;
      const int b = m >> 11, l = m & 2047;
#pragma unroll
      for (int ci = 0; ci < 2; ++ci)
#pragma unroll
        for (int j = 0; j < 4; ++j) {
          const int n = n0 + ci * 64 + tx * 4 + j;
          const float v = acc[ri][ci][i][j] + bias[n];
          const int h = n & 7, c = n >> 3;
          dst[((b * NH + h) * SEQ + l) * HD + c] = v;
        }
    }
}

// ---------------------------------------------------------------------------
// Flash attention (fp32 vector). Grid (32 qtiles, 16 bh). 512 threads.
// BQ=64, BKV=64. Q/K/V staged in LDS with XOR f4-column swizzle:
//   element (r,k) stored at column-f4  (k>>2) ^ ((r>>2)&7)
// which spreads the per-lane row-varying fragment reads across bank quads.
// ---------------------------------------------------------------------------
#define ATT_SMEM_BYTES ((3 * 64 * 128 + 64 * 68) * 4)  // 115712

__global__ __launch_bounds__(512, 2) void attn_kernel(const float* __restrict__ ws,
                                                      const int* __restrict__ mask,
                                                      float* __restrict__ A) {
  extern __shared__ float sm[];
  float (*Qs)[128] = (float(*)[128])sm;
  float (*Ks)[128] = (float(*)[128])(sm + 64 * 128);
  float (*Vs)[128] = (float(*)[128])(sm + 2 * 64 * 128);
  float (*Ps)[68]  = (float(*)[68])(sm + 3 * 64 * 128);

  const int qb = blockIdx.x;
  const int bh = blockIdx.y;          // b*8 + h
  const int b = bh >> 3, h = bh & 7;
  const int t = threadIdx.x;
  const int tx = t & 15;              // score col group (16 lanes per row-group)
  const int ty = t >> 4;              // 0..31, rows = ty*2 + {0,1}
  const int q0 = qb * 64;

  const float* Qg = ws + WS_Q + bh * (SEQ * HD);
  const float* Kg = ws + WS_K + bh * (SEQ * HD);
  const float* Vg = ws + WS_V + bh * (SEQ * HD);

  // Q tile: 64x128 = 2048 f4, 4 per thread, swizzled store
#pragma unroll
  for (int i = 0; i < 4; ++i) {
    const int f = t + i * 512;
    const int r = f >> 5, c4 = f & 31;
    const int sc = (c4 ^ ((r >> 2) & 7)) * 4;
    *reinterpret_cast<float4*>(&Qs[r][sc]) = ldg4(Qg + (q0 + r) * HD + c4 * 4);
  }

  const int row0 = ty * 2;
  float m_run[2] = {-3.0e38f, -3.0e38f};
  float l_run[2] = {0.f, 0.f};
  float o[2][2][4];
#pragma unroll
  for (int j = 0; j < 2; ++j)
#pragma unroll
    for (int hh = 0; hh < 2; ++hh)
#pragma unroll
      for (int d = 0; d < 4; ++d) o[j][hh][d] = 0.f;

  for (int kt = 0; kt < SEQ / 64; ++kt) {
    const int k0 = kt * 64;
    __syncthreads();
#pragma unroll
    for (int i = 0; i < 4; ++i) {
      const int f = t + i * 512;
      const int r = f >> 5, c4 = f & 31;
      const int sc = (c4 ^ ((r >> 2) & 7)) * 4;
      *reinterpret_cast<float4*>(&Ks[r][sc]) = ldg4(Kg + (k0 + r) * HD + c4 * 4);
      *reinterpret_cast<float4*>(&Vs[r][sc]) = ldg4(Vg + (k0 + r) * HD + c4 * 4);
    }
    __syncthreads();

    // scores: 2 rows x 4 cols, k=128 dot
    float s[2][4];
#pragma unroll
    for (int j = 0; j < 2; ++j)
#pragma unroll
      for (int i = 0; i < 4; ++i) s[j][i] = 0.f;

#pragma unroll 8
    for (int k4 = 0; k4 < 32; ++k4) {
      float4 qv[2], kv[4];
#pragma unroll
      for (int j = 0; j < 2; ++j) {
        const int r = row0 + j;
        qv[j] = *reinterpret_cast<const float4*>(&Qs[r][(k4 ^ ((r >> 2) & 7)) * 4]);
      }
#pragma unroll
      for (int i = 0; i < 4; ++i) {
        const int r = tx * 4 + i;  // (r>>2)&7 == tx&7
        kv[i] = *reinterpret_cast<const float4*>(&Ks[r][(k4 ^ (tx & 7)) * 4]);
      }
#pragma unroll
      for (int j = 0; j < 2; ++j)
#pragma unroll
        for (int i = 0; i < 4; ++i) {
          s[j][i] = fmaf(qv[j].x, kv[i].x, s[j][i]);
          s[j][i] = fmaf(qv[j].y, kv[i].y, s[j][i]);
          s[j][i] = fmaf(qv[j].z, kv[i].z, s[j][i]);
          s[j][i] = fmaf(qv[j].w, kv[i].w, s[j][i]);
        }
    }

    // mask + scale + online softmax (per row, reduce over 16 tx lanes)
#pragma unroll
    for (int j = 0; j < 2; ++j) {
      const int grow = q0 + row0 + j;
      const int4 mv = *reinterpret_cast<const int4*>(&mask[(b * SEQ + grow) * SEQ + k0 + tx * 4]);
      s[j][0] = mv.x ? -1e10f : s[j][0] * 0.03125f;
      s[j][1] = mv.y ? -1e10f : s[j][1] * 0.03125f;
      s[j][2] = mv.z ? -1e10f : s[j][2] * 0.03125f;
      s[j][3] = mv.w ? -1e10f : s[j][3] * 0.03125f;

      float tm = fmaxf(fmaxf(s[j][0], s[j][1]), fmaxf(s[j][2], s[j][3]));
#pragma unroll
      for (int off = 1; off < 16; off <<= 1) tm = fmaxf(tm, __shfl_xor(tm, off, 64));
      const float mn = fmaxf(m_run[j], tm);
      const float sf = __expf(m_run[j] - mn);
      m_run[j] = mn;
      float rs = 0.f;
#pragma unroll
      for (int i = 0; i < 4; ++i) { const float p = __expf(s[j][i] - mn); s[j][i] = p; rs += p; }
#pragma unroll
      for (int off = 1; off < 16; off <<= 1) rs += __shfl_xor(rs, off, 64);
      l_run[j] = l_run[j] * sf + rs;
#pragma unroll
      for (int hh = 0; hh < 2; ++hh)
#pragma unroll
        for (int d = 0; d < 4; ++d) o[j][hh][d] *= sf;
      *reinterpret_cast<float4*>(&Ps[row0 + j][tx * 4]) =
          make_float4(s[j][0], s[j][1], s[j][2], s[j][3]);
    }

    // PV: o[j][.][.] += sum_c P[row][c] * V[c][dd], dd = tx*4 / 64+tx*4
#pragma unroll 4
    for (int c4 = 0; c4 < 16; ++c4) {
      float4 pv[2];
#pragma unroll
      for (int j = 0; j < 2; ++j)
        pv[j] = *reinterpret_cast<const float4*>(&Ps[row0 + j][c4 * 4]);  // intra-wave, broadcast
#pragma unroll
      for (int ci = 0; ci < 4; ++ci) {
        const int c = c4 * 4 + ci;
        const int sw = (c >> 2) & 7;
        const float4 v0 = *reinterpret_cast<const float4*>(&Vs[c][(tx ^ sw) * 4]);
        const float4 v1 = *reinterpret_cast<const float4*>(&Vs[c][((16 + tx) ^ sw) * 4]);
#pragma unroll
        for (int j = 0; j < 2; ++j) {
          const float pc = getc(pv[j], ci);
          o[j][0][0] = fmaf(pc, v0.x, o[j][0][0]);
          o[j][0][1] = fmaf(pc, v0.y, o[j][0][1]);
          o[j][0][2] = fmaf(pc, v0.z, o[j][0][2]);
          o[j][0][3] = fmaf(pc, v0.w, o[j][0][3]);
          o[j][1][0] = fmaf(pc, v1.x, o[j][1][0]);
          o[j][1][1] = fmaf(pc, v1.y, o[j][1][1]);
          o[j][1][2] = fmaf(pc, v1.z, o[j][1][2]);
          o[j][1][3] = fmaf(pc, v1.w, o[j][1][3]);
        }
      }
    }
  }

  // epilogue: contiguous head concat a[b, l, h*128 + c]
#pragma unroll
  for (int j = 0; j < 2; ++j) {
    const float inv = 1.f / l_run[j];
    const int grow = q0 + row0 + j;
    float* dst = A + (b * SEQ + grow) * D_MODEL + h * HD;
    float4 r0 = make_float4(o[j][0][0] * inv, o[j][0][1] * inv, o[j][0][2] * inv, o[j][0][3] * inv);
    float4 r1 = make_float4(o[j][1][0] * inv, o[j][1][1] * inv, o[j][1][2] * inv, o[j][1][3] * inv);
    *reinterpret_cast<float4*>(dst + tx * 4)      = r0;
    *reinterpret_cast<float4*>(dst + 64 + tx * 4) = r1;
  }
}

// ---------------------------------------------------------------------------
// Output projection: R = A@Wo + bo + de
// ---------------------------------------------------------------------------
__global__ __launch_bounds__(256) void outproj_kernel(const float* __restrict__ ws,
                                                      const float* __restrict__ Wo,
                                                      const float* __restrict__ bo,
                                                      const float* __restrict__ de,
                                                      float* __restrict__ R) {
  const float* A = ws + WS_A;
  const int m0 = blockIdx.y * 128, n0 = blockIdx.x * 128;
  float acc[2][2][4][4];
  gemm_core_1024(A, Wo, m0, n0, acc);
  const int t = threadIdx.x, tx = t & 15, ty = t >> 4;
#pragma unroll
  for (int ri = 0; ri < 2; ++ri)
#pragma unroll
    for (int i = 0; i < 4; ++i) {
      const int m = m0 + ri * 64 + ty * 4 + i;
#pragma unroll
      for (int ci = 0; ci < 2; ++ci) {
        const int n = n0 + ci * 64 + tx * 4;
        const float4 dv = ldg4(de + m * D_MODEL + n);
        const float4 bv = ldg4(bo + n);
        float4 ov;
        ov.x = acc[ri][ci][i][0] + bv.x + dv.x;
        ov.y = acc[ri][ci][i][1] + bv.y + dv.y;
        ov.z = acc[ri][ci][i][2] + bv.z + dv.z;
        ov.w = acc[ri][ci][i][3] + bv.w + dv.w;
        *reinterpret_cast<float4*>(&R[m * D_MODEL + n]) = ov;
      }
    }
}

// ---------------------------------------------------------------------------
// LayerNorm, unbiased var (ddof=1), eps=1e-8. One block (256 thr) per row.
// ---------------------------------------------------------------------------
__global__ __launch_bounds__(256) void ln_kernel(const float* __restrict__ R,
                                                 const float* __restrict__ gptr,
                                                 const float* __restrict__ bptr,
                                                 float* __restrict__ out) {
  __shared__ float red[8];
  const int m = blockIdx.x, t = threadIdx.x;
  const int lane = t & 63, wid = t >> 6;
  const float4 x = ldg4(R + m * D_MODEL + t * 4);
  float s = x.x + x.y + x.z + x.w;
#pragma unroll
  for (int off = 1; off < 64; off <<= 1) s += __shfl_xor(s, off, 64);
  if (lane == 0) red[wid] = s;
  __syncthreads();
  const float mu = (red[0] + red[1] + red[2] + red[3]) * (1.f / 1024.f);
  const float dx = x.x - mu, dy = x.y - mu, dz = x.z - mu, dw = x.w - mu;
  float sq = dx * dx + dy * dy + dz * dz + dw * dw;
#pragma unroll
  for (int off = 1; off < 64; off <<= 1) sq += __shfl_xor(sq, off, 64);
  if (lane == 0) red[4 + wid] = sq;
  __syncthreads();
  const float var = (red[4] + red[5] + red[6] + red[7]) * (1.f / 1023.f);
  const float inv = rsqrtf(var + 1e-8f);
  const float g = gptr[0], be = bptr[0];
  float4 ov;
  ov.x = g * dx * inv + be;
  ov.y = g * dy * inv + be;
  ov.z = g * dz * inv + be;
  ov.w = g * dw * inv + be;
  *reinterpret_cast<float4*>(&out[m * D_MODEL + t * 4]) = ov;
}

// ---------------------------------------------------------------------------
extern "C" void kernel_launch(void* const* d_in, const int* in_sizes, int n_in,
                              void* d_out, int out_size, void* d_ws, size_t ws_size,
                              hipStream_t stream) {
  const float* en   = (const float*)d_in[0];
  const float* de   = (const float*)d_in[1];
  const int*   mask = (const int*)d_in[2];
  const float* Wq   = (const float*)d_in[3];
  const float* bq   = (const float*)d_in[4];
  const float* Wk   = (const float*)d_in[5];
  const float* bk   = (const float*)d_in[6];
  const float* Wv   = (const float*)d_in[7];
  const float* bv   = (const float*)d_in[8];
  const float* Wo   = (const float*)d_in[9];
  const float* bo   = (const float*)d_in[10];
  const float* gamma = (const float*)d_in[11];
  const float* beta  = (const float*)d_in[12];
  float* ws  = (float*)d_ws;
  float* out = (float*)d_out;

  // allow >64KB dynamic LDS for attention (idempotent; same work every call)
  (void)hipFuncSetAttribute(reinterpret_cast<const void*>(attn_kernel),
                            hipFuncAttributeMaxDynamicSharedMemorySize, ATT_SMEM_BYTES);

  qkv_kernel<<<dim3(8, 32, 3), 256, 0, stream>>>(de, en, Wq, bq, Wk, bk, Wv, bv, ws);
  attn_kernel<<<dim3(32, 16), 512, ATT_SMEM_BYTES, stream>>>(ws, mask, ws + WS_A);
  outproj_kernel<<<dim3(8, 32), 256, 0, stream>>>(ws, Wo, bo, de, ws + WS_R);
  ln_kernel<<<MTOT, 256, 0, stream>>>(ws + WS_R, gamma, beta, out);
}

// Round 2
// 769.762 us; speedup vs baseline: 1.8329x; 1.8329x over previous
//
#include <hip/hip_runtime.h>
#include <hip/hip_bf16.h>

// Problem constants
#define D_MODEL 1024
#define SEQ     2048
#define BATCH   2
#define NH      8
#define HD      128   // D_MODEL / NH
#define MTOT    4096  // BATCH * SEQ

// Workspace layout (float offsets)
#define WS_A 0          // attention output fp32, [b][l][h*128+c]  (4M floats)
#define WS_R 4194304    // pre-LN result fp32                      (4M floats)
#define WS_BF 8388608   // bf16 region starts here (byte 32MB):
                        //   Qb  [bh][l][c]  4M bf16
                        //   Kb  [bh][l][c]  4M bf16
                        //   Vtb [bh][c][l]  4M bf16

typedef __attribute__((ext_vector_type(4))) float f32x4;
typedef __attribute__((ext_vector_type(8))) short bf16x8;

__device__ __forceinline__ float4 ldg4(const float* p) {
  return *reinterpret_cast<const float4*>(p);
}

// ---------------------------------------------------------------------------
// GEMM core (fp32 vector): C[128x128] tile = X[128xK] * W[Kx128], K=1024.
// ---------------------------------------------------------------------------
__device__ __forceinline__ void gemm_core_1024(const float* __restrict__ X,
                                               const float* __restrict__ W,
                                               int m0, int n0,
                                               float acc[2][2][4][4]) {
  __shared__ float As[2][16][132];
  __shared__ float Bs[2][16][132];
  const int t  = threadIdx.x;
  const int tx = t & 15, ty = t >> 4;
  const int ar = t >> 1, ac = (t & 1) * 8;
  const int br = t >> 4, bc = (t & 15) * 8;

#pragma unroll
  for (int a = 0; a < 2; ++a)
#pragma unroll
    for (int b = 0; b < 2; ++b)
#pragma unroll
      for (int i = 0; i < 4; ++i)
#pragma unroll
        for (int j = 0; j < 4; ++j) acc[a][b][i][j] = 0.f;

  const float* Ap = X + (m0 + ar) * D_MODEL + ac;
  const float* Bp = W + br * D_MODEL + n0 + bc;

  float4 a0 = ldg4(Ap), a1 = ldg4(Ap + 4);
  float4 b0 = ldg4(Bp), b1 = ldg4(Bp + 4);
  {
    float av[8] = {a0.x, a0.y, a0.z, a0.w, a1.x, a1.y, a1.z, a1.w};
#pragma unroll
    for (int i = 0; i < 8; ++i) As[0][ac + i][ar] = av[i];
    *reinterpret_cast<float4*>(&Bs[0][br][bc])     = b0;
    *reinterpret_cast<float4*>(&Bs[0][br][bc + 4]) = b1;
  }

  const int NSTEP = D_MODEL / 16;
  for (int ks = 0; ks < NSTEP; ++ks) {
    __syncthreads();
    const int cb = ks & 1;
    if (ks + 1 < NSTEP) {
      a0 = ldg4(Ap + (ks + 1) * 16);
      a1 = ldg4(Ap + (ks + 1) * 16 + 4);
      b0 = ldg4(Bp + (ks + 1) * 16 * D_MODEL);
      b1 = ldg4(Bp + (ks + 1) * 16 * D_MODEL + 4);
    }
#pragma unroll
    for (int k = 0; k < 16; ++k) {
      float4 xa0 = *reinterpret_cast<const float4*>(&As[cb][k][ty * 4]);
      float4 xa1 = *reinterpret_cast<const float4*>(&As[cb][k][64 + ty * 4]);
      float4 xb0 = *reinterpret_cast<const float4*>(&Bs[cb][k][tx * 4]);
      float4 xb1 = *reinterpret_cast<const float4*>(&Bs[cb][k][64 + tx * 4]);
      float aa[2][4] = {{xa0.x, xa0.y, xa0.z, xa0.w}, {xa1.x, xa1.y, xa1.z, xa1.w}};
      float bb[2][4] = {{xb0.x, xb0.y, xb0.z, xb0.w}, {xb1.x, xb1.y, xb1.z, xb1.w}};
#pragma unroll
      for (int ri = 0; ri < 2; ++ri)
#pragma unroll
        for (int i = 0; i < 4; ++i)
#pragma unroll
          for (int ci = 0; ci < 2; ++ci)
#pragma unroll
            for (int j = 0; j < 4; ++j)
              acc[ri][ci][i][j] = fmaf(aa[ri][i], bb[ci][j], acc[ri][ci][i][j]);
    }
    if (ks + 1 < NSTEP) {
      const int nb = cb ^ 1;
      float av[8] = {a0.x, a0.y, a0.z, a0.w, a1.x, a1.y, a1.z, a1.w};
#pragma unroll
      for (int i = 0; i < 8; ++i) As[nb][ac + i][ar] = av[i];
      *reinterpret_cast<float4*>(&Bs[nb][br][bc])     = b0;
      *reinterpret_cast<float4*>(&Bs[nb][br][bc + 4]) = b1;
    }
  }
}

// ---------------------------------------------------------------------------
// QKV projection -> bf16 outputs for MFMA attention.
// z=0: Qb[bh][l][c], z=1: Kb[bh][l][c], z=2: Vtb[bh][c][l] (pre-transposed).
// Head split faithful to reference: h = n%8, c = n/8.
// ---------------------------------------------------------------------------
__global__ __launch_bounds__(256) void qkv_kernel(const float* __restrict__ de,
                                                  const float* __restrict__ en,
                                                  const float* __restrict__ Wq, const float* __restrict__ bq,
                                                  const float* __restrict__ Wk, const float* __restrict__ bk,
                                                  const float* __restrict__ Wv, const float* __restrict__ bv,
                                                  __hip_bfloat16* __restrict__ Qb,
                                                  __hip_bfloat16* __restrict__ Kb,
                                                  __hip_bfloat16* __restrict__ Vtb) {
  const int z = blockIdx.z;
  const float* X    = (z == 0) ? de : en;
  const float* W    = (z == 0) ? Wq : (z == 1) ? Wk : Wv;
  const float* bias = (z == 0) ? bq : (z == 1) ? bk : bv;
  const int m0 = blockIdx.y * 128, n0 = blockIdx.x * 128;
  float acc[2][2][4][4];
  gemm_core_1024(X, W, m0, n0, acc);
  const int t = threadIdx.x, tx = t & 15, ty = t >> 4;
#pragma unroll
  for (int ri = 0; ri < 2; ++ri)
#pragma unroll
    for (int i = 0; i < 4; ++i) {
      const int m = m0 + ri * 64 + ty * 4 + i;
      const int b = m >> 11, l = m & 2047;
#pragma unroll
      for (int ci = 0; ci < 2; ++ci)
#pragma unroll
        for (int j = 0; j < 4; ++j) {
          const int n = n0 + ci * 64 + tx * 4 + j;
          const float v = acc[ri][ci][i][j] + bias[n];
          const int h = n & 7, c = n >> 3;
          const __hip_bfloat16 bv16 = __float2bfloat16(v);
          if (z == 2) {
            Vtb[((size_t)(b * NH + h) * HD + c) * SEQ + l] = bv16;
          } else {
            __hip_bfloat16* dst = (z == 0) ? Qb : Kb;
            dst[((size_t)(b * NH + h) * SEQ + l) * HD + c] = bv16;
          }
        }
    }
}

// ---------------------------------------------------------------------------
// MFMA flash attention (bf16 inputs, fp32 accum/softmax).
// Grid (32 qtiles, 16 bh), 256 threads = 4 waves. BQ=64 (16 rows/wave), BKV=64.
// mfma_f32_16x16x32_bf16: A row = lane&15, B col = lane&15, k-order any
// (consistent between A & B); D: col = lane&15, row = (lane>>4)*4 + i.
// ---------------------------------------------------------------------------
__global__ __launch_bounds__(256, 2) void attn_kernel(const __hip_bfloat16* __restrict__ Qb,
                                                      const __hip_bfloat16* __restrict__ Kb,
                                                      const __hip_bfloat16* __restrict__ Vtb,
                                                      const int* __restrict__ mask,
                                                      float* __restrict__ A) {
  __shared__ __hip_bfloat16 Qs[64][136];  // [q][chan], 272B rows (16B-mult, 4-bank skew)
  __shared__ __hip_bfloat16 Ks[64][136];  // [kv][chan]
  __shared__ __hip_bfloat16 Vt[128][72];  // [d][kv], 144B rows
  __shared__ __hip_bfloat16 Ps[64][72];   // [q][kv], per-wave 16-row slices

  const int qb = blockIdx.x, bh = blockIdx.y;
  const int b = bh >> 3, h = bh & 7;
  const int t = threadIdx.x;
  const int w = t >> 6, l = t & 63;
  const int lr = l & 15, lg = l >> 4;
  const int q0 = qb * 64;

  const __hip_bfloat16* Qg = Qb + (size_t)bh * SEQ * HD;
  const __hip_bfloat16* Kg = Kb + (size_t)bh * SEQ * HD;
  const __hip_bfloat16* Vg = Vtb + (size_t)bh * HD * SEQ;

  // Q tile: 64 rows x 128 chan = 1024 16B chunks, 4/thread
#pragma unroll
  for (int it = 0; it < 4; ++it) {
    const int idx = t + it * 256;
    const int r = idx >> 4, cc = idx & 15;
    *reinterpret_cast<uint4*>(&Qs[r][cc * 8]) =
        *reinterpret_cast<const uint4*>(Qg + (size_t)(q0 + r) * HD + cc * 8);
  }

  float m_run[4], l_run[4];
  f32x4 o[8];
#pragma unroll
  for (int i = 0; i < 4; ++i) { m_run[i] = -INFINITY; l_run[i] = 0.f; }
#pragma unroll
  for (int dt = 0; dt < 8; ++dt) o[dt] = (f32x4){0.f, 0.f, 0.f, 0.f};

  for (int kt = 0; kt < SEQ / 64; ++kt) {
    const int k0 = kt * 64;
    __syncthreads();
#pragma unroll
    for (int it = 0; it < 4; ++it) {
      const int idx = t + it * 256;
      const int r = idx >> 4, cc = idx & 15;
      *reinterpret_cast<uint4*>(&Ks[r][cc * 8]) =
          *reinterpret_cast<const uint4*>(Kg + (size_t)(k0 + r) * HD + cc * 8);
      const int d = idx >> 3, ck = idx & 7;
      *reinterpret_cast<uint4*>(&Vt[d][ck * 8]) =
          *reinterpret_cast<const uint4*>(Vg + (size_t)d * SEQ + k0 + ck * 8);
    }
    __syncthreads();

    // S = Q K^T : wave's 16 rows x 64 cols
    f32x4 s[4];
#pragma unroll
    for (int nt = 0; nt < 4; ++nt) s[nt] = (f32x4){0.f, 0.f, 0.f, 0.f};
#pragma unroll
    for (int kc = 0; kc < 4; ++kc) {
      const bf16x8 afr = *reinterpret_cast<const bf16x8*>(&Qs[w * 16 + lr][kc * 32 + lg * 8]);
#pragma unroll
      for (int nt = 0; nt < 4; ++nt) {
        const bf16x8 bfr = *reinterpret_cast<const bf16x8*>(&Ks[nt * 16 + lr][kc * 32 + lg * 8]);
        s[nt] = __builtin_amdgcn_mfma_f32_16x16x32_bf16(afr, bfr, s[nt], 0, 0, 0);
      }
    }

    // mask + scale + online softmax; rows handled by this lane: lg*4+i
    const int* mbase = mask + ((size_t)b * SEQ + q0 + w * 16 + lg * 4) * SEQ + k0 + lr;
    float p[4][4];  // [nt][i]
#pragma unroll
    for (int i = 0; i < 4; ++i) {
      const int* mrow = mbase + (size_t)i * SEQ;
      float v0 = mrow[0]  ? -1e10f : s[0][i] * 0.03125f;
      float v1 = mrow[16] ? -1e10f : s[1][i] * 0.03125f;
      float v2 = mrow[32] ? -1e10f : s[2][i] * 0.03125f;
      float v3 = mrow[48] ? -1e10f : s[3][i] * 0.03125f;
      p[0][i] = v0; p[1][i] = v1; p[2][i] = v2; p[3][i] = v3;

      float rm = fmaxf(fmaxf(v0, v1), fmaxf(v2, v3));
      rm = fmaxf(rm, __shfl_xor(rm, 1, 64));
      rm = fmaxf(rm, __shfl_xor(rm, 2, 64));
      rm = fmaxf(rm, __shfl_xor(rm, 4, 64));
      rm = fmaxf(rm, __shfl_xor(rm, 8, 64));
      const float mn = fmaxf(m_run[i], rm);
      const float sf = __expf(m_run[i] - mn);
      m_run[i] = mn;
      float rs = 0.f;
#pragma unroll
      for (int nt = 0; nt < 4; ++nt) {
        const float pe = __expf(p[nt][i] - mn);
        p[nt][i] = pe;
        rs += pe;
      }
      rs += __shfl_xor(rs, 1, 64);
      rs += __shfl_xor(rs, 2, 64);
      rs += __shfl_xor(rs, 4, 64);
      rs += __shfl_xor(rs, 8, 64);
      l_run[i] = l_run[i] * sf + rs;
#pragma unroll
      for (int dt = 0; dt < 8; ++dt) o[dt][i] *= sf;
      // P -> LDS (bf16), wave-private rows: no barrier needed
#pragma unroll
      for (int nt = 0; nt < 4; ++nt)
        Ps[w * 16 + lg * 4 + i][nt * 16 + lr] = __float2bfloat16(p[nt][i]);
    }

    // O += P V : rows q (A from Ps), cols d (B from Vt)
#pragma unroll
    for (int ks = 0; ks < 2; ++ks) {
      const bf16x8 pa = *reinterpret_cast<const bf16x8*>(&Ps[w * 16 + lr][ks * 32 + lg * 8]);
#pragma unroll
      for (int dt = 0; dt < 8; ++dt) {
        const bf16x8 vb = *reinterpret_cast<const bf16x8*>(&Vt[dt * 16 + lr][ks * 32 + lg * 8]);
        o[dt] = __builtin_amdgcn_mfma_f32_16x16x32_bf16(pa, vb, o[dt], 0, 0, 0);
      }
    }
  }

  // epilogue: A[b][q][h*128 + d] fp32
  float* Ab = A + ((size_t)b * SEQ + q0 + w * 16 + lg * 4) * D_MODEL + h * HD + lr;
#pragma unroll
  for (int i = 0; i < 4; ++i) {
    const float inv = 1.f / l_run[i];
#pragma unroll
    for (int dt = 0; dt < 8; ++dt)
      Ab[(size_t)i * D_MODEL + dt * 16] = o[dt][i] * inv;
  }
}

// ---------------------------------------------------------------------------
// Output projection: R = A@Wo + bo + de
// ---------------------------------------------------------------------------
__global__ __launch_bounds__(256) void outproj_kernel(const float* __restrict__ A,
                                                      const float* __restrict__ Wo,
                                                      const float* __restrict__ bo,
                                                      const float* __restrict__ de,
                                                      float* __restrict__ R) {
  const int m0 = blockIdx.y * 128, n0 = blockIdx.x * 128;
  float acc[2][2][4][4];
  gemm_core_1024(A, Wo, m0, n0, acc);
  const int t = threadIdx.x, tx = t & 15, ty = t >> 4;
#pragma unroll
  for (int ri = 0; ri < 2; ++ri)
#pragma unroll
    for (int i = 0; i < 4; ++i) {
      const int m = m0 + ri * 64 + ty * 4 + i;
#pragma unroll
      for (int ci = 0; ci < 2; ++ci) {
        const int n = n0 + ci * 64 + tx * 4;
        const float4 dv = ldg4(de + m * D_MODEL + n);
        const float4 bv = ldg4(bo + n);
        float4 ov;
        ov.x = acc[ri][ci][i][0] + bv.x + dv.x;
        ov.y = acc[ri][ci][i][1] + bv.y + dv.y;
        ov.z = acc[ri][ci][i][2] + bv.z + dv.z;
        ov.w = acc[ri][ci][i][3] + bv.w + dv.w;
        *reinterpret_cast<float4*>(&R[m * D_MODEL + n]) = ov;
      }
    }
}

// ---------------------------------------------------------------------------
// LayerNorm, unbiased var (ddof=1), eps=1e-8. One block (256 thr) per row.
// ---------------------------------------------------------------------------
__global__ __launch_bounds__(256) void ln_kernel(const float* __restrict__ R,
                                                 const float* __restrict__ gptr,
                                                 const float* __restrict__ bptr,
                                                 float* __restrict__ out) {
  __shared__ float red[8];
  const int m = blockIdx.x, t = threadIdx.x;
  const int lane = t & 63, wid = t >> 6;
  const float4 x = ldg4(R + m * D_MODEL + t * 4);
  float s = x.x + x.y + x.z + x.w;
#pragma unroll
  for (int off = 1; off < 64; off <<= 1) s += __shfl_xor(s, off, 64);
  if (lane == 0) red[wid] = s;
  __syncthreads();
  const float mu = (red[0] + red[1] + red[2] + red[3]) * (1.f / 1024.f);
  const float dx = x.x - mu, dy = x.y - mu, dz = x.z - mu, dw = x.w - mu;
  float sq = dx * dx + dy * dy + dz * dz + dw * dw;
#pragma unroll
  for (int off = 1; off < 64; off <<= 1) sq += __shfl_xor(sq, off, 64);
  if (lane == 0) red[4 + wid] = sq;
  __syncthreads();
  const float var = (red[4] + red[5] + red[6] + red[7]) * (1.f / 1023.f);
  const float inv = rsqrtf(var + 1e-8f);
  const float g = gptr[0], be = bptr[0];
  float4 ov;
  ov.x = g * dx * inv + be;
  ov.y = g * dy * inv + be;
  ov.z = g * dz * inv + be;
  ov.w = g * dw * inv + be;
  *reinterpret_cast<float4*>(&out[m * D_MODEL + t * 4]) = ov;
}

// ---------------------------------------------------------------------------
extern "C" void kernel_launch(void* const* d_in, const int* in_sizes, int n_in,
                              void* d_out, int out_size, void* d_ws, size_t ws_size,
                              hipStream_t stream) {
  const float* en   = (const float*)d_in[0];
  const float* de   = (const float*)d_in[1];
  const int*   mask = (const int*)d_in[2];
  const float* Wq   = (const float*)d_in[3];
  const float* bq   = (const float*)d_in[4];
  const float* Wk   = (const float*)d_in[5];
  const float* bk   = (const float*)d_in[6];
  const float* Wv   = (const float*)d_in[7];
  const float* bv   = (const float*)d_in[8];
  const float* Wo   = (const float*)d_in[9];
  const float* bo   = (const float*)d_in[10];
  const float* gamma = (const float*)d_in[11];
  const float* beta  = (const float*)d_in[12];
  float* ws  = (float*)d_ws;
  float* out = (float*)d_out;

  __hip_bfloat16* Qb  = (__hip_bfloat16*)(ws + WS_BF);
  __hip_bfloat16* Kb  = Qb + (size_t)4194304;
  __hip_bfloat16* Vtb = Kb + (size_t)4194304;

  qkv_kernel<<<dim3(8, 32, 3), 256, 0, stream>>>(de, en, Wq, bq, Wk, bk, Wv, bv, Qb, Kb, Vtb);
  attn_kernel<<<dim3(32, 16), 256, 0, stream>>>(Qb, Kb, Vtb, mask, ws + WS_A);
  outproj_kernel<<<dim3(8, 32), 256, 0, stream>>>(ws + WS_A, Wo, bo, de, ws + WS_R);
  ln_kernel<<<MTOT, 256, 0, stream>>>(ws + WS_R, gamma, beta, out);
}

// Round 5
// 339.170 us; speedup vs baseline: 4.1598x; 2.2695x over previous
//
#include <hip/hip_runtime.h>
#include <hip/hip_bf16.h>

// Problem constants
#define D_MODEL 1024
#define SEQ     2048
#define BATCH   2
#define NH      8
#define HD      128   // D_MODEL / NH
#define MTOT    4096  // BATCH * SEQ

typedef __attribute__((ext_vector_type(4))) float f32x4;
typedef __attribute__((ext_vector_type(8))) short bf16x8;

// Workspace: fp32 R occupies ws[0..4M) floats; bf16 region starts at ws+4M.
// bf16 element offsets within the bf16 region:
#define BF_XDE 0u          // [m][k] 4M
#define BF_XEN 4194304u    // [m][k] 4M
#define BF_WQT 8388608u    // [n][k] 1M
#define BF_WKT 9437184u
#define BF_WVT 10485760u
#define BF_WOT 11534336u
#define BF_QB  12582912u   // [bh][l][c] 4M
#define BF_KB  16777216u
#define BF_VT  20971520u   // [bh][c][l] 4M
#define BF_AB  25165824u   // [m][n] 4M (attention out)

__device__ __forceinline__ float4 ldg4(const float* p) {
  return *reinterpret_cast<const float4*>(p);
}

__device__ __forceinline__ void load_lds16(const void* g, void* l) {
  __builtin_amdgcn_global_load_lds((const __attribute__((address_space(1))) void*)g,
                                   (__attribute__((address_space(3))) void*)l, 16, 0, 0);
}

// ---------------------------------------------------------------------------
// Cast activations fp32 -> bf16 row-major [m][k]. 1024x2 blocks, 16 elem/thr.
// ---------------------------------------------------------------------------
__global__ __launch_bounds__(256) void castx_kernel(const float* __restrict__ de,
                                                    const float* __restrict__ en,
                                                    __hip_bfloat16* __restrict__ Xde,
                                                    __hip_bfloat16* __restrict__ Xen) {
  const float* src = blockIdx.y ? en : de;
  __hip_bfloat16* dst = blockIdx.y ? Xen : Xde;
  const size_t base = (size_t)blockIdx.x * 4096 + (size_t)threadIdx.x * 16;
  float tmp[16];
#pragma unroll
  for (int i = 0; i < 4; ++i) {
    const float4 v = ldg4(src + base + i * 4);
    tmp[i * 4 + 0] = v.x; tmp[i * 4 + 1] = v.y; tmp[i * 4 + 2] = v.z; tmp[i * 4 + 3] = v.w;
  }
  __hip_bfloat16 ob[16];
#pragma unroll
  for (int i = 0; i < 16; ++i) ob[i] = __float2bfloat16(tmp[i]);
  *reinterpret_cast<uint4*>(dst + base)     = *reinterpret_cast<const uint4*>(ob);
  *reinterpret_cast<uint4*>(dst + base + 8) = *reinterpret_cast<const uint4*>(ob + 8);
}

// ---------------------------------------------------------------------------
// Cast + transpose weights: W[k][n] fp32 -> Wt[n][k] bf16. 64x64 tiles.
// ---------------------------------------------------------------------------
__global__ __launch_bounds__(256) void castw_kernel(const float* __restrict__ Wq,
                                                    const float* __restrict__ Wk,
                                                    const float* __restrict__ Wv,
                                                    const float* __restrict__ Wo,
                                                    __hip_bfloat16* __restrict__ WtBase) {
  __shared__ __hip_bfloat16 tile[64][68];
  const int z = blockIdx.z;
  const float* W = (z == 0) ? Wq : (z == 1) ? Wk : (z == 2) ? Wv : Wo;
  __hip_bfloat16* Wt = WtBase + (size_t)z * 1048576;
  const int n0 = blockIdx.x * 64, k0 = blockIdx.y * 64;
  const int t = threadIdx.x;
#pragma unroll
  for (int i = 0; i < 4; ++i) {
    const int kr = (t >> 4) + i * 16, cg = t & 15;
    const float4 v = ldg4(W + (size_t)(k0 + kr) * D_MODEL + n0 + cg * 4);
    __hip_bfloat16 tb[4] = {__float2bfloat16(v.x), __float2bfloat16(v.y),
                            __float2bfloat16(v.z), __float2bfloat16(v.w)};
    *reinterpret_cast<ushort4*>(&tile[kr][cg * 4]) = *reinterpret_cast<const ushort4*>(tb);
  }
  __syncthreads();
  const int nr = t >> 2, ks = (t & 3) * 16;
  __hip_bfloat16 ob[16];
#pragma unroll
  for (int j = 0; j < 16; ++j) ob[j] = tile[ks + j][nr];
  __hip_bfloat16* dst = Wt + (size_t)(n0 + nr) * D_MODEL + k0 + ks;
  *reinterpret_cast<uint4*>(dst)     = *reinterpret_cast<const uint4*>(ob);
  *reinterpret_cast<uint4*>(dst + 8) = *reinterpret_cast<const uint4*>(ob + 8);
}

// ---------------------------------------------------------------------------
// MFMA GEMM core (m97 structure): C 128x128 tile = A[m][k] * Bt[n][k]^T,
// K=1024, BK=64, 4 waves 2x2, global_load_lds width-16 staging, 2 barriers/step.
// ---------------------------------------------------------------------------
__device__ __forceinline__ void mfma_core(const __hip_bfloat16* __restrict__ Ag,
                                          const __hip_bfloat16* __restrict__ Bg,
                                          int m0, int n0,
                                          __hip_bfloat16* Asm, __hip_bfloat16* Bsm,
                                          f32x4 acc[4][4]) {
  const int t = threadIdx.x, w = t >> 6, l = t & 63;
  const int lr = l & 15, lg = l >> 4;
  const int wr = w >> 1, wc = w & 1;
  const int lrow = l >> 3;           // within-chunk row (8 rows of 128B per chunk)
  const int lcol = (l & 7) * 8;      // k-element offset within row

#pragma unroll
  for (int a = 0; a < 4; ++a)
#pragma unroll
    for (int b = 0; b < 4; ++b) acc[a][b] = (f32x4){0.f, 0.f, 0.f, 0.f};

  for (int ks = 0; ks < D_MODEL / 64; ++ks) {
    __syncthreads();  // previous step's reads complete before overwrite
#pragma unroll
    for (int j = 0; j < 4; ++j) {
      const int chunk = w * 4 + j;     // 16 chunks x 8 rows = 128 rows
      const int row = chunk * 8 + lrow;
      load_lds16(Ag + (size_t)(m0 + row) * D_MODEL + ks * 64 + lcol, Asm + chunk * 512);
      load_lds16(Bg + (size_t)(n0 + row) * D_MODEL + ks * 64 + lcol, Bsm + chunk * 512);
    }
    __syncthreads();  // syncthreads drains vmcnt -> staging visible
#pragma unroll
    for (int kk = 0; kk < 2; ++kk) {
      bf16x8 af[4], bf[4];
#pragma unroll
      for (int fm = 0; fm < 4; ++fm)
        af[fm] = *reinterpret_cast<const bf16x8*>(Asm + (wr * 64 + fm * 16 + lr) * 64 + kk * 32 + lg * 8);
#pragma unroll
      for (int fn = 0; fn < 4; ++fn)
        bf[fn] = *reinterpret_cast<const bf16x8*>(Bsm + (wc * 64 + fn * 16 + lr) * 64 + kk * 32 + lg * 8);
#pragma unroll
      for (int fm = 0; fm < 4; ++fm)
#pragma unroll
        for (int fn = 0; fn < 4; ++fn)
          acc[fm][fn] = __builtin_amdgcn_mfma_f32_16x16x32_bf16(af[fm], bf[fn], acc[fm][fn], 0, 0, 0);
    }
  }
}

// ---------------------------------------------------------------------------
// QKV GEMM: z=0 Q=Xde@Wq, z=1 K=Xen@Wk, z=2 V=Xen@Wv. Epilogue: +bias,
// head split (h=n%8, c=n/8), bf16 out; V transposed [bh][c][l].
// ---------------------------------------------------------------------------
__global__ __launch_bounds__(256, 2) void gemm_qkv_kernel(
    const __hip_bfloat16* __restrict__ Xde, const __hip_bfloat16* __restrict__ Xen,
    const __hip_bfloat16* __restrict__ WtQ,  // base of Wqt; +z*1M selects
    const float* __restrict__ bq, const float* __restrict__ bk, const float* __restrict__ bv,
    __hip_bfloat16* __restrict__ Qb, __hip_bfloat16* __restrict__ Kb,
    __hip_bfloat16* __restrict__ Vt) {
  __shared__ __hip_bfloat16 Asm[128 * 64];
  __shared__ __hip_bfloat16 Bsm[128 * 64];
  const int z = blockIdx.z;
  const __hip_bfloat16* Ag = (z == 0) ? Xde : Xen;
  const __hip_bfloat16* Bg = WtQ + (size_t)z * 1048576;
  const float* bias = (z == 0) ? bq : (z == 1) ? bk : bv;
  const int m0 = blockIdx.y * 128, n0 = blockIdx.x * 128;
  f32x4 acc[4][4];
  mfma_core(Ag, Bg, m0, n0, Asm, Bsm, acc);

  const int t = threadIdx.x, w = t >> 6, l = t & 63;
  const int lr = l & 15, lg = l >> 4, wr = w >> 1, wc = w & 1;
#pragma unroll
  for (int fn = 0; fn < 4; ++fn) {
    const int n = n0 + wc * 64 + fn * 16 + lr;
    const float bve = bias[n];
    const int h = n & 7, c = n >> 3;
#pragma unroll
    for (int fm = 0; fm < 4; ++fm)
#pragma unroll
      for (int i = 0; i < 4; ++i) {
        const int m = m0 + wr * 64 + fm * 16 + lg * 4 + i;
        const int b = m >> 11, ll = m & 2047;
        const __hip_bfloat16 v = __float2bfloat16(acc[fm][fn][i] + bve);
        if (z == 2) Vt[((size_t)(b * NH + h) * HD + c) * SEQ + ll] = v;
        else {
          __hip_bfloat16* dst = (z == 0) ? Qb : Kb;
          dst[((size_t)(b * NH + h) * SEQ + ll) * HD + c] = v;
        }
      }
  }
}

// ---------------------------------------------------------------------------
// Out projection: R = Ab@Wo + bo + de  (fp32 out for LN)
// ---------------------------------------------------------------------------
__global__ __launch_bounds__(256, 2) void gemm_out_kernel(
    const __hip_bfloat16* __restrict__ Ab, const __hip_bfloat16* __restrict__ Wot,
    const float* __restrict__ bo, const float* __restrict__ de,
    float* __restrict__ R) {
  __shared__ __hip_bfloat16 Asm[128 * 64];
  __shared__ __hip_bfloat16 Bsm[128 * 64];
  const int m0 = blockIdx.y * 128, n0 = blockIdx.x * 128;
  f32x4 acc[4][4];
  mfma_core(Ab, Wot, m0, n0, Asm, Bsm, acc);

  const int t = threadIdx.x, w = t >> 6, l = t & 63;
  const int lr = l & 15, lg = l >> 4, wr = w >> 1, wc = w & 1;
#pragma unroll
  for (int fn = 0; fn < 4; ++fn) {
    const int n = n0 + wc * 64 + fn * 16 + lr;
    const float bve = bo[n];
#pragma unroll
    for (int fm = 0; fm < 4; ++fm)
#pragma unroll
      for (int i = 0; i < 4; ++i) {
        const int m = m0 + wr * 64 + fm * 16 + lg * 4 + i;
        R[(size_t)m * D_MODEL + n] = acc[fm][fn][i] + bve + de[(size_t)m * D_MODEL + n];
      }
  }
}

// ---------------------------------------------------------------------------
// MFMA flash attention (unchanged structure from R2; epilogue now bf16 -> Ab)
// ---------------------------------------------------------------------------
__global__ __launch_bounds__(256, 2) void attn_kernel(const __hip_bfloat16* __restrict__ Qb,
                                                      const __hip_bfloat16* __restrict__ Kb,
                                                      const __hip_bfloat16* __restrict__ Vtb,
                                                      const int* __restrict__ mask,
                                                      __hip_bfloat16* __restrict__ Ab) {
  __shared__ __hip_bfloat16 Qs[64][136];
  __shared__ __hip_bfloat16 Ks[64][136];
  __shared__ __hip_bfloat16 Vt[128][72];
  __shared__ __hip_bfloat16 Ps[64][72];

  const int qb = blockIdx.x, bh = blockIdx.y;
  const int b = bh >> 3, h = bh & 7;
  const int t = threadIdx.x;
  const int w = t >> 6, l = t & 63;
  const int lr = l & 15, lg = l >> 4;
  const int q0 = qb * 64;

  const __hip_bfloat16* Qg = Qb + (size_t)bh * SEQ * HD;
  const __hip_bfloat16* Kg = Kb + (size_t)bh * SEQ * HD;
  const __hip_bfloat16* Vg = Vtb + (size_t)bh * HD * SEQ;

#pragma unroll
  for (int it = 0; it < 4; ++it) {
    const int idx = t + it * 256;
    const int r = idx >> 4, cc = idx & 15;
    *reinterpret_cast<uint4*>(&Qs[r][cc * 8]) =
        *reinterpret_cast<const uint4*>(Qg + (size_t)(q0 + r) * HD + cc * 8);
  }

  float m_run[4], l_run[4];
  f32x4 o[8];
#pragma unroll
  for (int i = 0; i < 4; ++i) { m_run[i] = -INFINITY; l_run[i] = 0.f; }
#pragma unroll
  for (int dt = 0; dt < 8; ++dt) o[dt] = (f32x4){0.f, 0.f, 0.f, 0.f};

  for (int kt = 0; kt < SEQ / 64; ++kt) {
    const int k0 = kt * 64;
    __syncthreads();
#pragma unroll
    for (int it = 0; it < 4; ++it) {
      const int idx = t + it * 256;
      const int r = idx >> 4, cc = idx & 15;
      *reinterpret_cast<uint4*>(&Ks[r][cc * 8]) =
          *reinterpret_cast<const uint4*>(Kg + (size_t)(k0 + r) * HD + cc * 8);
      const int d = idx >> 3, ck = idx & 7;
      *reinterpret_cast<uint4*>(&Vt[d][ck * 8]) =
          *reinterpret_cast<const uint4*>(Vg + (size_t)d * SEQ + k0 + ck * 8);
    }
    __syncthreads();

    f32x4 s[4];
#pragma unroll
    for (int nt = 0; nt < 4; ++nt) s[nt] = (f32x4){0.f, 0.f, 0.f, 0.f};
#pragma unroll
    for (int kc = 0; kc < 4; ++kc) {
      const bf16x8 afr = *reinterpret_cast<const bf16x8*>(&Qs[w * 16 + lr][kc * 32 + lg * 8]);
#pragma unroll
      for (int nt = 0; nt < 4; ++nt) {
        const bf16x8 bfr = *reinterpret_cast<const bf16x8*>(&Ks[nt * 16 + lr][kc * 32 + lg * 8]);
        s[nt] = __builtin_amdgcn_mfma_f32_16x16x32_bf16(afr, bfr, s[nt], 0, 0, 0);
      }
    }

    const int* mbase = mask + ((size_t)b * SEQ + q0 + w * 16 + lg * 4) * SEQ + k0 + lr;
    float p[4][4];
#pragma unroll
    for (int i = 0; i < 4; ++i) {
      const int* mrow = mbase + (size_t)i * SEQ;
      float v0 = mrow[0]  ? -1e10f : s[0][i] * 0.03125f;
      float v1 = mrow[16] ? -1e10f : s[1][i] * 0.03125f;
      float v2 = mrow[32] ? -1e10f : s[2][i] * 0.03125f;
      float v3 = mrow[48] ? -1e10f : s[3][i] * 0.03125f;
      p[0][i] = v0; p[1][i] = v1; p[2][i] = v2; p[3][i] = v3;

      float rm = fmaxf(fmaxf(v0, v1), fmaxf(v2, v3));
      rm = fmaxf(rm, __shfl_xor(rm, 1, 64));
      rm = fmaxf(rm, __shfl_xor(rm, 2, 64));
      rm = fmaxf(rm, __shfl_xor(rm, 4, 64));
      rm = fmaxf(rm, __shfl_xor(rm, 8, 64));
      const float mn = fmaxf(m_run[i], rm);
      const float sf = __expf(m_run[i] - mn);
      m_run[i] = mn;
      float rs = 0.f;
#pragma unroll
      for (int nt = 0; nt < 4; ++nt) {
        const float pe = __expf(p[nt][i] - mn);
        p[nt][i] = pe;
        rs += pe;
      }
      rs += __shfl_xor(rs, 1, 64);
      rs += __shfl_xor(rs, 2, 64);
      rs += __shfl_xor(rs, 4, 64);
      rs += __shfl_xor(rs, 8, 64);
      l_run[i] = l_run[i] * sf + rs;
#pragma unroll
      for (int dt = 0; dt < 8; ++dt) o[dt][i] *= sf;
#pragma unroll
      for (int nt = 0; nt < 4; ++nt)
        Ps[w * 16 + lg * 4 + i][nt * 16 + lr] = __float2bfloat16(p[nt][i]);
    }

#pragma unroll
    for (int ksb = 0; ksb < 2; ++ksb) {
      const bf16x8 pa = *reinterpret_cast<const bf16x8*>(&Ps[w * 16 + lr][ksb * 32 + lg * 8]);
#pragma unroll
      for (int dt = 0; dt < 8; ++dt) {
        const bf16x8 vb = *reinterpret_cast<const bf16x8*>(&Vt[dt * 16 + lr][ksb * 32 + lg * 8]);
        o[dt] = __builtin_amdgcn_mfma_f32_16x16x32_bf16(pa, vb, o[dt], 0, 0, 0);
      }
    }
  }

  // epilogue: Ab[b][q][h*128 + d] bf16
  __hip_bfloat16* Abp = Ab + ((size_t)b * SEQ + q0 + w * 16 + lg * 4) * D_MODEL + h * HD + lr;
#pragma unroll
  for (int i = 0; i < 4; ++i) {
    const float inv = 1.f / l_run[i];
#pragma unroll
    for (int dt = 0; dt < 8; ++dt)
      Abp[(size_t)i * D_MODEL + dt * 16] = __float2bfloat16(o[dt][i] * inv);
  }
}

// ---------------------------------------------------------------------------
// LayerNorm, unbiased var (ddof=1), eps=1e-8. One block (256 thr) per row.
// ---------------------------------------------------------------------------
__global__ __launch_bounds__(256) void ln_kernel(const float* __restrict__ R,
                                                 const float* __restrict__ gptr,
                                                 const float* __restrict__ bptr,
                                                 float* __restrict__ out) {
  __shared__ float red[8];
  const int m = blockIdx.x, t = threadIdx.x;
  const int lane = t & 63, wid = t >> 6;
  const float4 x = ldg4(R + (size_t)m * D_MODEL + t * 4);
  float s = x.x + x.y + x.z + x.w;
#pragma unroll
  for (int off = 1; off < 64; off <<= 1) s += __shfl_xor(s, off, 64);
  if (lane == 0) red[wid] = s;
  __syncthreads();
  const float mu = (red[0] + red[1] + red[2] + red[3]) * (1.f / 1024.f);
  const float dx = x.x - mu, dy = x.y - mu, dz = x.z - mu, dw = x.w - mu;
  float sq = dx * dx + dy * dy + dz * dz + dw * dw;
#pragma unroll
  for (int off = 1; off < 64; off <<= 1) sq += __shfl_xor(sq, off, 64);
  if (lane == 0) red[4 + wid] = sq;
  __syncthreads();
  const float var = (red[4] + red[5] + red[6] + red[7]) * (1.f / 1023.f);
  const float inv = rsqrtf(var + 1e-8f);
  const float g = gptr[0], be = bptr[0];
  float4 ov;
  ov.x = g * dx * inv + be;
  ov.y = g * dy * inv + be;
  ov.z = g * dz * inv + be;
  ov.w = g * dw * inv + be;
  *reinterpret_cast<float4*>(&out[(size_t)m * D_MODEL + t * 4]) = ov;
}

// ---------------------------------------------------------------------------
extern "C" void kernel_launch(void* const* d_in, const int* in_sizes, int n_in,
                              void* d_out, int out_size, void* d_ws, size_t ws_size,
                              hipStream_t stream) {
  const float* en   = (const float*)d_in[0];
  const float* de   = (const float*)d_in[1];
  const int*   mask = (const int*)d_in[2];
  const float* Wq   = (const float*)d_in[3];
  const float* bq   = (const float*)d_in[4];
  const float* Wk   = (const float*)d_in[5];
  const float* bk   = (const float*)d_in[6];
  const float* Wv   = (const float*)d_in[7];
  const float* bv   = (const float*)d_in[8];
  const float* Wo   = (const float*)d_in[9];
  const float* bo   = (const float*)d_in[10];
  const float* gamma = (const float*)d_in[11];
  const float* beta  = (const float*)d_in[12];
  float* ws  = (float*)d_ws;
  float* out = (float*)d_out;

  float* R = ws;                                            // 4M floats
  __hip_bfloat16* bfb = (__hip_bfloat16*)(ws + 4194304);    // bf16 region
  __hip_bfloat16* Xde = bfb + BF_XDE;
  __hip_bfloat16* Xen = bfb + BF_XEN;
  __hip_bfloat16* Wqt = bfb + BF_WQT;   // Wkt/Wvt/Wot follow at +1M each
  __hip_bfloat16* Wot = bfb + BF_WOT;
  __hip_bfloat16* Qb  = bfb + BF_QB;
  __hip_bfloat16* Kb  = bfb + BF_KB;
  __hip_bfloat16* Vt  = bfb + BF_VT;
  __hip_bfloat16* Ab  = bfb + BF_AB;

  castx_kernel<<<dim3(1024, 2), 256, 0, stream>>>(de, en, Xde, Xen);
  castw_kernel<<<dim3(16, 16, 4), 256, 0, stream>>>(Wq, Wk, Wv, Wo, Wqt);
  gemm_qkv_kernel<<<dim3(8, 32, 3), 256, 0, stream>>>(Xde, Xen, Wqt, bq, bk, bv, Qb, Kb, Vt);
  attn_kernel<<<dim3(32, 16), 256, 0, stream>>>(Qb, Kb, Vt, mask, Ab);
  gemm_out_kernel<<<dim3(8, 32), 256, 0, stream>>>(Ab, Wot, bo, de, R);
  ln_kernel<<<MTOT, 256, 0, stream>>>(R, gamma, beta, out);
}